// Round 2
// baseline (427.499 us; speedup 1.0000x reference)
//
#include <hip/hip_runtime.h>
#include <math.h>

// ---------------------------------------------------------------------------
// AttnBlock: per-edge radial-MLP attention logits + segment softmax over dst.
//
// Structure (3 stream ops):
//   memset ssum[N]=0 (double)
//   K1 edge:  dot[e] -> d_out (fp32), atomicAdd ssum[v[e]] += exp((double)dot)
//   K2 norm:  d_out[e] = (float)( exp((double)dot) / ssum[v[e]] )
//
// fp64 exp/sum/divide replaces the per-node max pass: exp range +-709 in
// double strictly dominates the achievable |dot| (LN bounds the MLP output),
// so this is exactly the max-stabilized softmax without the extra E-sweep.
//
// R5 change (this round): WAVE-PER-MLP decomposition. Previous version ran
// all 4 radial MLPs serially in one thread (4 long dependent chains,
// ~14KB unrolled body) at 42% occupancy / 47% VALUBusy => latency-bound.
// Now: block = 4 waves = 64 edges; wave w runs MLP w for the block's 64
// edges (weight pointers wave-uniform via readfirstlane => weights stay
// scalar-cache loads). Serial chain per wave /4, wave parallelism x4,
// code size ~/4 (single shared MLP body). Per-wave partial dot (the q.k
// epilogue is linear in per-MLP contributions) -> LDS -> wave 0 reduces,
// writes out, does the fp64 atomic.
//
// wj01/wj10/wj11 staged into LDS with coalesced float4 loads (R4 win);
// stride-27/3 LDS rows are odd strides -> 2 lanes/bank = conflict-free.
// ---------------------------------------------------------------------------

#define TPB 256
#define EPB 64  // edges per block

typedef float f2 __attribute__((ext_vector_type(2)));
typedef float f4 __attribute__((ext_vector_type(4)));

static __device__ __forceinline__ f2 fma2(f2 a, f2 b, f2 c) {
    return __builtin_elementwise_fma(a, b, c);
}
static __device__ __forceinline__ f2 splat(float x) {
    f2 r;
    r.x = x;
    r.y = x;
    return r;
}
static __device__ __forceinline__ float get16(const f2* h, int c) {
    return (c & 1) ? h[c >> 1].y : h[c >> 1].x;
}

// LayerNorm(16) + ReLU over h[8] (packed pairs). g/be are f2-aligned.
static __device__ __forceinline__ void ln_relu16(f2* h, const float* __restrict__ g,
                                                 const float* __restrict__ be) {
    const f2* g2 = (const f2*)g;
    const f2* be2 = (const f2*)be;
    f2 s = h[0] + h[1] + h[2] + h[3] + h[4] + h[5] + h[6] + h[7];
    const float mu = (s.x + s.y) * 0.0625f;
    const f2 mu2 = splat(mu);
    f2 vs = splat(0.f);
#pragma unroll
    for (int i = 0; i < 8; ++i) {
        f2 d = h[i] - mu2;
        vs = fma2(d, d, vs);
    }
    const float var = (vs.x + vs.y) * 0.0625f;
    const f2 r2 = splat(rsqrtf(var + 1e-5f));
    const f2 zero = splat(0.f);
#pragma unroll
    for (int i = 0; i < 8; ++i) {
        f2 t = (h[i] - mu2) * r2;
        h[i] = __builtin_elementwise_max(fma2(t, g2[i], be2[i]), zero);
    }
}

// layers 1..2 of a radial MLP: vec(3) -> 16 -> LN/relu -> 16 -> LN/relu
static __device__ __forceinline__ void radial_h2(
    float v0, float v1, float v2, const float* __restrict__ W1,
    const float* __restrict__ b1, const float* __restrict__ g1,
    const float* __restrict__ be1, const float* __restrict__ W2,
    const float* __restrict__ b2, const float* __restrict__ g2,
    const float* __restrict__ be2, f2* h2) {
    const f2* W1r0 = (const f2*)W1;
    const f2* W1r1 = (const f2*)(W1 + 16);
    const f2* W1r2 = (const f2*)(W1 + 32);
    const f2* b1v = (const f2*)b1;
    const f2 a = splat(v0), b = splat(v1), c = splat(v2);
    f2 h[8];
#pragma unroll
    for (int j = 0; j < 8; ++j)
        h[j] = fma2(a, W1r0[j], fma2(b, W1r1[j], fma2(c, W1r2[j], b1v[j])));
    ln_relu16(h, g1, be1);

    const f2* b2v = (const f2*)b2;
#pragma unroll
    for (int j = 0; j < 8; ++j) h2[j] = b2v[j];
#pragma unroll
    for (int c16 = 0; c16 < 16; ++c16) {
        const f2 hc = splat(get16(h, c16));
        const f2* row = (const f2*)(W2 + c16 * 16);
#pragma unroll
        for (int j = 0; j < 8; ++j) h2[j] = fma2(hc, row[j], h2[j]);
    }
    ln_relu16(h2, g2, be2);
}

// layer3 for OUT=4: p0={R0(o0i0),R1(o0i1)}, p1={R2(o1i0),R3(o1i1)}
static __device__ __forceinline__ void layer3_4(const f2* h2,
                                                const float* __restrict__ W3,
                                                const float* __restrict__ b3,
                                                f2& p0, f2& p1) {
    p0 = *(const f2*)(b3);
    p1 = *(const f2*)(b3 + 2);
#pragma unroll
    for (int c = 0; c < 16; ++c) {
        const f2 hc = splat(get16(h2, c));
        p0 = fma2(hc, *(const f2*)(W3 + c * 4), p0);
        p1 = fma2(hc, *(const f2*)(W3 + c * 4 + 2), p1);
    }
}

__global__ __launch_bounds__(TPB, 6) void edge_kernel(
    const float* __restrict__ f0, const float* __restrict__ f1,
    const float* __restrict__ dist, const int* __restrict__ u,
    const int* __restrict__ v, const float* __restrict__ wq,
    const float* __restrict__ wj00, const float* __restrict__ wj01,
    const float* __restrict__ wj10, const float* __restrict__ wj11,
    const float* __restrict__ rW1, const float* __restrict__ rb1,
    const float* __restrict__ g1, const float* __restrict__ be1,
    const float* __restrict__ rW2, const float* __restrict__ rb2,
    const float* __restrict__ g2, const float* __restrict__ be2,
    const float* __restrict__ W3_00, const float* __restrict__ b3_00,
    const float* __restrict__ W3_01, const float* __restrict__ b3_01,
    const float* __restrict__ W3_10, const float* __restrict__ b3_10,
    const float* __restrict__ W3_11, const float* __restrict__ b3_11,
    float* __restrict__ out, double* __restrict__ ssum, int E) {
    __shared__ __align__(16) float s11[EPB * 27];
    __shared__ __align__(16) float s01[EPB * 3];
    __shared__ __align__(16) float s10[EPB * 3];
    __shared__ float pdot[4][EPB];

    const int tid = threadIdx.x;
    const int base = blockIdx.x * EPB;
    const int rem = E - base;
    const int nE = (rem < EPB) ? rem : EPB;

    // ---- coalesced staging of the per-edge wj tensors for this slab ----
    if (nE == EPB) {
        const f4* s11s = (const f4*)(wj11 + (size_t)base * 27);
        f4* s11d = (f4*)s11;
#pragma unroll 2
        for (int i = tid; i < EPB * 27 / 4; i += TPB) s11d[i] = s11s[i];
        if (tid < EPB * 3 / 4) {
            ((f4*)s01)[tid] = ((const f4*)(wj01 + (size_t)base * 3))[tid];
            ((f4*)s10)[tid] = ((const f4*)(wj10 + (size_t)base * 3))[tid];
        }
    } else {
        for (int i = tid; i < nE * 27; i += TPB) s11[i] = wj11[(size_t)base * 27 + i];
        for (int i = tid; i < nE * 3; i += TPB) {
            s01[i] = wj01[(size_t)base * 3 + i];
            s10[i] = wj10[(size_t)base * 3 + i];
        }
    }
    __syncthreads();

    const int lane = tid & 63;
    const int w = __builtin_amdgcn_readfirstlane(tid >> 6);  // wave-uniform MLP id
    const int e = base + lane;

    float dotw = 0.f;
    int vv = 0;
    if (e < E) {
        const int uu = u[e];
        vv = v[e];

        const f2 f0u = *(const f2*)(f0 + (size_t)uu * 2);
        const f2 f0v2 = *(const f2*)(f0 + (size_t)vv * 2);
        const float f0v0 = f0v2.x;
        const float f0v1 = f0v2.y;

        float f1v[2][3];
        if (w != 0) {  // waves 1..3 need the degree-1 dst feature
            const f2 f1a = *(const f2*)(f1 + (size_t)vv * 6);
            const f2 f1b = *(const f2*)(f1 + (size_t)vv * 6 + 2);
            const f2 f1c = *(const f2*)(f1 + (size_t)vv * 6 + 4);
            f1v[0][0] = f1a.x; f1v[0][1] = f1a.y; f1v[0][2] = f1b.x;
            f1v[1][0] = f1b.y; f1v[1][1] = f1c.x; f1v[1][2] = f1c.y;
        }

        const float vec0 = f0u.x * f0v0;
        const float vec1 = f0u.y * f0v1;
        const float vec2 = dist[e];

        // shared MLP body; weight pointers are wave-uniform (SGPR base)
        f2 h2[8];
        radial_h2(vec0, vec1, vec2, rW1 + w * 48, rb1 + w * 16, g1 + w * 16,
                  be1 + w * 16, rW2 + w * 256, rb2 + w * 16, g2 + w * 16,
                  be2 + w * 16, h2);

        if (w == 0) {  // (l=0,k=0)
            f2 p0, p1;
            layer3_4(h2, W3_00, b3_00, p0, p1);
            const float wj = wj00[e];
            const float a0 = wj * (p0.x * f0v0 + p0.y * f0v1);
            const float a1 = wj * (p1.x * f0v0 + p1.y * f0v1);
            const float q00 = wq[0] * f0v0 + wq[1] * f0v1;
            const float q01 = wq[2] * f0v0 + wq[3] * f0v1;
            dotw = q00 * a0 + q01 * a1;
        } else if (w == 1) {  // (l=0,k=1)
            f2 p0, p1;
            layer3_4(h2, W3_01, b3_01, p0, p1);
            const float* my01 = s01 + lane * 3;
            const float w0 = my01[0];
            const float w1 = my01[1];
            const float w2 = my01[2];
            const float s0 = w0 * f1v[0][0] + w1 * f1v[0][1] + w2 * f1v[0][2];
            const float s1 = w0 * f1v[1][0] + w1 * f1v[1][1] + w2 * f1v[1][2];
            const float a0 = p0.x * s0 + p0.y * s1;
            const float a1 = p1.x * s0 + p1.y * s1;
            const float q00 = wq[0] * f0v0 + wq[1] * f0v1;
            const float q01 = wq[2] * f0v0 + wq[3] * f0v1;
            dotw = q00 * a0 + q01 * a1;
        } else if (w == 2) {  // (l=1,k=0)
            f2 p0, p1;
            layer3_4(h2, W3_10, b3_10, p0, p1);
            const float t0 = p0.x * f0v0 + p0.y * f0v1;
            const float t1 = p1.x * f0v0 + p1.y * f0v1;
            const float* my10 = s10 + lane * 3;
#pragma unroll
            for (int m = 0; m < 3; ++m) {
                const float wm = my10[m];
                const float q1m0 = wq[4] * f1v[0][m] + wq[5] * f1v[1][m];
                const float q1m1 = wq[6] * f1v[0][m] + wq[7] * f1v[1][m];
                dotw += q1m0 * (wm * t0) + q1m1 * (wm * t1);
            }
        } else {  // (l=1,k=1)
            const float* my11 = s11 + lane * 27;
            float acc1[2][3] = {{0.f, 0.f, 0.f}, {0.f, 0.f, 0.f}};
#pragma unroll
            for (int j = 0; j < 3; ++j) {
                f2 p0 = *(const f2*)(b3_11 + j * 4);
                f2 p1 = *(const f2*)(b3_11 + j * 4 + 2);
#pragma unroll
                for (int c = 0; c < 16; ++c) {
                    const f2 hc = splat(get16(h2, c));
                    p0 = fma2(hc, *(const f2*)(W3_11 + c * 12 + j * 4), p0);
                    p1 = fma2(hc, *(const f2*)(W3_11 + c * 12 + j * 4 + 2), p1);
                }
#pragma unroll
                for (int m = 0; m < 3; ++m) {
                    const float w0 = my11[j * 9 + m * 3 + 0];
                    const float w1 = my11[j * 9 + m * 3 + 1];
                    const float w2 = my11[j * 9 + m * 3 + 2];
                    const float B0 =
                        w0 * f1v[0][0] + w1 * f1v[0][1] + w2 * f1v[0][2];
                    const float B1 =
                        w0 * f1v[1][0] + w1 * f1v[1][1] + w2 * f1v[1][2];
                    acc1[0][m] += p0.x * B0 + p0.y * B1;
                    acc1[1][m] += p1.x * B0 + p1.y * B1;
                }
            }
#pragma unroll
            for (int m = 0; m < 3; ++m) {
                const float q1m0 = wq[4] * f1v[0][m] + wq[5] * f1v[1][m];
                const float q1m1 = wq[6] * f1v[0][m] + wq[7] * f1v[1][m];
                dotw += q1m0 * acc1[0][m] + q1m1 * acc1[1][m];
            }
        }
    }

    pdot[w][lane] = dotw;
    __syncthreads();

    if (w == 0 && e < E) {
        const float dot =
            pdot[0][lane] + pdot[1][lane] + pdot[2][lane] + pdot[3][lane];
        out[e] = dot;
        atomicAdd(&ssum[vv], exp((double)dot));
    }
}

__global__ void norm_kernel(float* __restrict__ out, const int* __restrict__ v,
                            const double* __restrict__ ssum, int E) {
    int e = blockIdx.x * blockDim.x + threadIdx.x;
    if (e >= E) return;
    const double t = exp((double)out[e]);
    out[e] = (float)(t / ssum[v[e]]);
}

extern "C" void kernel_launch(void* const* d_in, const int* in_sizes, int n_in,
                              void* d_out, int out_size, void* d_ws,
                              size_t ws_size, hipStream_t stream) {
    const float* f0 = (const float*)d_in[0];
    const float* f1 = (const float*)d_in[1];
    const float* dist = (const float*)d_in[2];
    const int* u = (const int*)d_in[3];
    const int* v = (const int*)d_in[4];
    const float* wq = (const float*)d_in[5];
    const float* wj00 = (const float*)d_in[6];
    const float* wj01 = (const float*)d_in[7];
    const float* wj10 = (const float*)d_in[8];
    const float* wj11 = (const float*)d_in[9];
    const float* rW1 = (const float*)d_in[10];
    const float* rb1 = (const float*)d_in[11];
    const float* g1 = (const float*)d_in[12];
    const float* be1 = (const float*)d_in[13];
    const float* rW2 = (const float*)d_in[14];
    const float* rb2 = (const float*)d_in[15];
    const float* g2 = (const float*)d_in[16];
    const float* be2 = (const float*)d_in[17];
    const float* W3_00 = (const float*)d_in[18];
    const float* b3_00 = (const float*)d_in[19];
    const float* W3_01 = (const float*)d_in[20];
    const float* b3_01 = (const float*)d_in[21];
    const float* W3_10 = (const float*)d_in[22];
    const float* b3_10 = (const float*)d_in[23];
    const float* W3_11 = (const float*)d_in[24];
    const float* b3_11 = (const float*)d_in[25];

    const int N = in_sizes[0] / 2;  // f0 is [N,2,1]
    const int E = in_sizes[2];      // dist is [E]

    double* ssum = (double*)d_ws;
    float* out = (float*)d_out;

    hipMemsetAsync(ssum, 0, (size_t)N * sizeof(double), stream);
    const int ge = (E + EPB - 1) / EPB;
    edge_kernel<<<ge, TPB, 0, stream>>>(
        f0, f1, dist, u, v, wq, wj00, wj01, wj10, wj11, rW1, rb1, g1, be1, rW2,
        rb2, g2, be2, W3_00, b3_00, W3_01, b3_01, W3_10, b3_10, W3_11, b3_11,
        out, ssum, E);
    const int gn = (E + TPB - 1) / TPB;
    norm_kernel<<<gn, TPB, 0, stream>>>(out, v, ssum, E);
}

// Round 4
// 406.088 us; speedup vs baseline: 1.0527x; 1.0527x over previous
//
#include <hip/hip_runtime.h>
#include <math.h>

// ---------------------------------------------------------------------------
// AttnBlock: per-edge radial-MLP attention logits + segment softmax over dst.
//
// Structure (3 stream ops):
//   memset ssum[N]=0 (double)
//   K1 edge:  dot[e] -> d_out (fp32), atomicAdd ssum[v[e]] += exp((double)dot)
//   K2 norm:  d_out[e] = (float)( exp((double)dot) / ssum[v[e]] )
//
// fp64 exp/sum/divide replaces the per-node max pass: exp range +-709 in
// double strictly dominates the achievable |dot| (LN bounds the MLP output),
// so this is exactly the max-stabilized softmax without the extra E-sweep.
//
// R7 = R6 resubmit (round-3 failure was infra: "container failed twice",
// with a degraded-harness 2500s npz push in the prior round's timing).
// Hardening only: padding region of sprep/sv zero-filled so no lane ever
// reads uninitialized LDS on the partial last slab.
//
// R6 design: EDGE-PAIR f2 PACKING + SHARED EDGE-PREP.
//  - Block = 4 waves, 128 edges. Wave w runs MLP w (wave-uniform weight
//    pointers -> s_load). Lane l handles edge pair (base+l, base+64+l).
//  - All f2 math packs the TWO EDGES in the vector halves: every
//    v_pk_fma_f32 does 2 edges' work, weights broadcast from SGPR (free),
//    LN horizontal reductions fully packed, dependent chain per edge /2.
//  - Prologue: threads 0..127 gather f0[u],f0[v],f1[v],dist ONCE per slab
//    into LDS; wj01/10/11 staged coalesced (R4 win).
//  - Per-wave partial dot (q.k epilogue is linear in per-MLP terms) ->
//    LDS -> wave 0 reduces, writes out, does the fp64 atomic for 2 edges.
// ---------------------------------------------------------------------------

#define TPB 256
#define EPB 128  // edges per block (= 2 per lane)

typedef float f2 __attribute__((ext_vector_type(2)));
typedef float f4 __attribute__((ext_vector_type(4)));

static __device__ __forceinline__ f2 fma2(f2 a, f2 b, f2 c) {
    return __builtin_elementwise_fma(a, b, c);
}
static __device__ __forceinline__ f2 splat(float x) {
    f2 r;
    r.x = x;
    r.y = x;
    return r;
}
static __device__ __forceinline__ f2 mk2(float a, float b) {
    f2 r;
    r.x = a;
    r.y = b;
    return r;
}

// LayerNorm(16)+ReLU, edge-pair packed: h[c] = {edgeA ch c, edgeB ch c}.
static __device__ __forceinline__ void ln_relu_pair(f2* h,
                                                    const float* __restrict__ g,
                                                    const float* __restrict__ be) {
    f2 s = ((h[0] + h[1]) + (h[2] + h[3])) + ((h[4] + h[5]) + (h[6] + h[7])) +
           (((h[8] + h[9]) + (h[10] + h[11])) +
            ((h[12] + h[13]) + (h[14] + h[15])));
    const f2 mu = s * splat(0.0625f);
    f2 vs = splat(0.f);
#pragma unroll
    for (int c = 0; c < 16; ++c) {
        f2 d = h[c] - mu;
        vs = fma2(d, d, vs);
    }
    const f2 var = vs * splat(0.0625f);
    f2 r;
    r.x = rsqrtf(var.x + 1e-5f);
    r.y = rsqrtf(var.y + 1e-5f);
    const f2 zero = splat(0.f);
#pragma unroll
    for (int c = 0; c < 16; ++c) {
        f2 t = (h[c] - mu) * r;
        h[c] = __builtin_elementwise_max(fma2(t, splat(g[c]), splat(be[c])), zero);
    }
}

// layers 1..2 of a radial MLP, edge-pair packed: vec(3)->16->LN/relu->16->LN/relu
static __device__ __forceinline__ void radial_pair(
    f2 v0, f2 v1, f2 v2, const float* __restrict__ W1,
    const float* __restrict__ b1, const float* __restrict__ g1,
    const float* __restrict__ be1, const float* __restrict__ W2,
    const float* __restrict__ b2, const float* __restrict__ g2,
    const float* __restrict__ be2, f2* h2) {
    f2 h[16];
#pragma unroll
    for (int c = 0; c < 16; ++c)
        h[c] = fma2(v0, splat(W1[c]),
                    fma2(v1, splat(W1[16 + c]),
                         fma2(v2, splat(W1[32 + c]), splat(b1[c]))));
    ln_relu_pair(h, g1, be1);

#pragma unroll
    for (int c2 = 0; c2 < 16; ++c2) h2[c2] = splat(b2[c2]);
#pragma unroll
    for (int c = 0; c < 16; ++c) {
#pragma unroll
        for (int c2 = 0; c2 < 16; ++c2)
            h2[c2] = fma2(h[c], splat(W2[c * 16 + c2]), h2[c2]);
    }
    ln_relu_pair(h2, g2, be2);
}

// layer3 (OUT=4), edge-pair packed: p[oi] for oi = o*2+i
static __device__ __forceinline__ void layer3_pair4(const f2* h2,
                                                    const float* __restrict__ W3,
                                                    const float* __restrict__ b3,
                                                    f2 p[4]) {
#pragma unroll
    for (int oi = 0; oi < 4; ++oi) p[oi] = splat(b3[oi]);
#pragma unroll
    for (int c = 0; c < 16; ++c) {
#pragma unroll
        for (int oi = 0; oi < 4; ++oi)
            p[oi] = fma2(h2[c], splat(W3[c * 4 + oi]), p[oi]);
    }
}

__global__ __launch_bounds__(TPB, 4) void edge_kernel(
    const float* __restrict__ f0, const float* __restrict__ f1,
    const float* __restrict__ dist, const int* __restrict__ u,
    const int* __restrict__ v, const float* __restrict__ wq,
    const float* __restrict__ wj00, const float* __restrict__ wj01,
    const float* __restrict__ wj10, const float* __restrict__ wj11,
    const float* __restrict__ rW1, const float* __restrict__ rb1,
    const float* __restrict__ g1, const float* __restrict__ be1,
    const float* __restrict__ rW2, const float* __restrict__ rb2,
    const float* __restrict__ g2, const float* __restrict__ be2,
    const float* __restrict__ W3_00, const float* __restrict__ b3_00,
    const float* __restrict__ W3_01, const float* __restrict__ b3_01,
    const float* __restrict__ W3_10, const float* __restrict__ b3_10,
    const float* __restrict__ W3_11, const float* __restrict__ b3_11,
    float* __restrict__ out, double* __restrict__ ssum, int E) {
    __shared__ __align__(16) float s11[EPB * 27];
    __shared__ __align__(16) float s01[EPB * 3];
    __shared__ __align__(16) float s10[EPB * 3];
    __shared__ __align__(16) float sprep[EPB * 12];
    __shared__ int sv[EPB];
    __shared__ f2 pdot[4][64];

    const int tid = threadIdx.x;
    const int base = blockIdx.x * EPB;
    const int rem = E - base;
    const int nE = (rem < EPB) ? rem : EPB;

    // ---- coalesced staging of per-edge wj tensors ----
    if (nE == EPB) {
        const f4* s11s = (const f4*)(wj11 + (size_t)base * 27);
        f4* s11d = (f4*)s11;
#pragma unroll 2
        for (int i = tid; i < EPB * 27 / 4; i += TPB) s11d[i] = s11s[i];
        if (tid < EPB * 3 / 4) {
            ((f4*)s01)[tid] = ((const f4*)(wj01 + (size_t)base * 3))[tid];
            ((f4*)s10)[tid] = ((const f4*)(wj10 + (size_t)base * 3))[tid];
        }
    } else {
        for (int i = tid; i < EPB * 27; i += TPB)
            s11[i] = (i < nE * 27) ? wj11[(size_t)base * 27 + i] : 0.f;
        for (int i = tid; i < EPB * 3; i += TPB) {
            s01[i] = (i < nE * 3) ? wj01[(size_t)base * 3 + i] : 0.f;
            s10[i] = (i < nE * 3) ? wj10[(size_t)base * 3 + i] : 0.f;
        }
    }

    // ---- shared edge prep: gathers done ONCE per slab ----
    if (tid < EPB) {
        const int e = base + tid;
        f4 t0 = {0.f, 0.f, 0.f, 0.f};
        f4 t1 = {0.f, 0.f, 0.f, 0.f};
        f4 t2 = {0.f, 0.f, 0.f, 0.f};
        int vv = 0;
        if (e < E) {
            const int uu = u[e];
            vv = v[e];
            const f2 f0u = *(const f2*)(f0 + (size_t)uu * 2);
            const f2 f0v2 = *(const f2*)(f0 + (size_t)vv * 2);
            const f2 f1a = *(const f2*)(f1 + (size_t)vv * 6);
            const f2 f1b = *(const f2*)(f1 + (size_t)vv * 6 + 2);
            const f2 f1c = *(const f2*)(f1 + (size_t)vv * 6 + 4);
            const float d = dist[e];
            t0.x = f0u.x * f0v2.x;  // vec0
            t0.y = f0u.y * f0v2.y;  // vec1
            t0.z = d;               // vec2
            t0.w = f0v2.x;          // f0v0
            t1.x = f0v2.y;          // f0v1
            t1.y = f1a.x;           // f1v[0][0]
            t1.z = f1a.y;           // f1v[0][1]
            t1.w = f1b.x;           // f1v[0][2]
            t2.x = f1b.y;           // f1v[1][0]
            t2.y = f1c.x;           // f1v[1][1]
            t2.z = f1c.y;           // f1v[1][2]
        }
        f4* dst = (f4*)(sprep + tid * 12);
        dst[0] = t0;
        dst[1] = t1;
        dst[2] = t2;
        sv[tid] = vv;
    }
    __syncthreads();

    const int l = tid & 63;
    const int w = __builtin_amdgcn_readfirstlane(tid >> 6);  // wave-uniform MLP id

    const float* pA = sprep + l * 12;
    const float* pB = sprep + (l + 64) * 12;
#define PR(k) mk2(pA[k], pB[k])
    const f2 vec0 = PR(0);
    const f2 vec1 = PR(1);
    const f2 vec2 = PR(2);
    const f2 f0v0 = PR(3);
    const f2 f0v1 = PR(4);
    f2 f1v[2][3];
    if (w != 0) {
        f1v[0][0] = PR(5);
        f1v[0][1] = PR(6);
        f1v[0][2] = PR(7);
        f1v[1][0] = PR(8);
        f1v[1][1] = PR(9);
        f1v[1][2] = PR(10);
    }
#undef PR

    f2 h2[16];
    radial_pair(vec0, vec1, vec2, rW1 + w * 48, rb1 + w * 16, g1 + w * 16,
                be1 + w * 16, rW2 + w * 256, rb2 + w * 16, g2 + w * 16,
                be2 + w * 16, h2);

    f2 dotp = splat(0.f);
    if (w == 0) {  // (l=0,k=0)
        f2 p[4];
        layer3_pair4(h2, W3_00, b3_00, p);
        const int eA = base + l, eB = eA + 64;
        f2 wj;
        wj.x = (eA < E) ? wj00[eA] : 0.f;
        wj.y = (eB < E) ? wj00[eB] : 0.f;
        const f2 a0 = wj * fma2(p[0], f0v0, p[1] * f0v1);
        const f2 a1 = wj * fma2(p[2], f0v0, p[3] * f0v1);
        const f2 q00 = fma2(splat(wq[0]), f0v0, splat(wq[1]) * f0v1);
        const f2 q01 = fma2(splat(wq[2]), f0v0, splat(wq[3]) * f0v1);
        dotp = fma2(q00, a0, q01 * a1);
    } else if (w == 1) {  // (l=0,k=1)
        f2 p[4];
        layer3_pair4(h2, W3_01, b3_01, p);
        const float* mA = s01 + l * 3;
        const float* mB = s01 + (l + 64) * 3;
        f2 s0 = splat(0.f), s1 = splat(0.f);
#pragma unroll
        for (int m = 0; m < 3; ++m) {
            const f2 wm = mk2(mA[m], mB[m]);
            s0 = fma2(wm, f1v[0][m], s0);
            s1 = fma2(wm, f1v[1][m], s1);
        }
        const f2 a0 = fma2(p[0], s0, p[1] * s1);
        const f2 a1 = fma2(p[2], s0, p[3] * s1);
        const f2 q00 = fma2(splat(wq[0]), f0v0, splat(wq[1]) * f0v1);
        const f2 q01 = fma2(splat(wq[2]), f0v0, splat(wq[3]) * f0v1);
        dotp = fma2(q00, a0, q01 * a1);
    } else if (w == 2) {  // (l=1,k=0)
        f2 p[4];
        layer3_pair4(h2, W3_10, b3_10, p);
        const f2 t0 = fma2(p[0], f0v0, p[1] * f0v1);
        const f2 t1 = fma2(p[2], f0v0, p[3] * f0v1);
        const float* mA = s10 + l * 3;
        const float* mB = s10 + (l + 64) * 3;
#pragma unroll
        for (int m = 0; m < 3; ++m) {
            const f2 wm = mk2(mA[m], mB[m]);
            const f2 q0 = fma2(splat(wq[4]), f1v[0][m], splat(wq[5]) * f1v[1][m]);
            const f2 q1 = fma2(splat(wq[6]), f1v[0][m], splat(wq[7]) * f1v[1][m]);
            dotp = fma2(q0 * wm, t0, dotp);
            dotp = fma2(q1 * wm, t1, dotp);
        }
    } else {  // (l=1,k=1)
        f2 p[3][4];
#pragma unroll
        for (int j = 0; j < 3; ++j)
#pragma unroll
            for (int oi = 0; oi < 4; ++oi) p[j][oi] = splat(b3_11[j * 4 + oi]);
#pragma unroll
        for (int c = 0; c < 16; ++c) {
#pragma unroll
            for (int j = 0; j < 3; ++j)
#pragma unroll
                for (int oi = 0; oi < 4; ++oi)
                    p[j][oi] = fma2(h2[c], splat(W3_11[c * 12 + j * 4 + oi]),
                                    p[j][oi]);
        }
        const float* mA = s11 + l * 27;
        const float* mB = s11 + (l + 64) * 27;
        f2 acc1[2][3];
#pragma unroll
        for (int m = 0; m < 3; ++m) {
            acc1[0][m] = splat(0.f);
            acc1[1][m] = splat(0.f);
        }
#pragma unroll
        for (int j = 0; j < 3; ++j) {
#pragma unroll
            for (int m = 0; m < 3; ++m) {
                const f2 w0 = mk2(mA[j * 9 + m * 3 + 0], mB[j * 9 + m * 3 + 0]);
                const f2 w1 = mk2(mA[j * 9 + m * 3 + 1], mB[j * 9 + m * 3 + 1]);
                const f2 w2 = mk2(mA[j * 9 + m * 3 + 2], mB[j * 9 + m * 3 + 2]);
                const f2 B0 =
                    fma2(w0, f1v[0][0], fma2(w1, f1v[0][1], w2 * f1v[0][2]));
                const f2 B1 =
                    fma2(w0, f1v[1][0], fma2(w1, f1v[1][1], w2 * f1v[1][2]));
                acc1[0][m] = fma2(p[j][0], B0, fma2(p[j][1], B1, acc1[0][m]));
                acc1[1][m] = fma2(p[j][2], B0, fma2(p[j][3], B1, acc1[1][m]));
            }
        }
#pragma unroll
        for (int m = 0; m < 3; ++m) {
            const f2 q0 = fma2(splat(wq[4]), f1v[0][m], splat(wq[5]) * f1v[1][m]);
            const f2 q1 = fma2(splat(wq[6]), f1v[0][m], splat(wq[7]) * f1v[1][m]);
            dotp = fma2(q0, acc1[0][m], dotp);
            dotp = fma2(q1, acc1[1][m], dotp);
        }
    }

    pdot[w][l] = dotp;
    __syncthreads();

    if (w == 0) {
        const f2 d =
            (pdot[0][l] + pdot[1][l]) + (pdot[2][l] + pdot[3][l]);
        const int eA = base + l, eB = eA + 64;
        if (eA < E) {
            out[eA] = d.x;
            atomicAdd(&ssum[sv[l]], exp((double)d.x));
        }
        if (eB < E) {
            out[eB] = d.y;
            atomicAdd(&ssum[sv[l + 64]], exp((double)d.y));
        }
    }
}

__global__ void norm_kernel(float* __restrict__ out, const int* __restrict__ v,
                            const double* __restrict__ ssum, int E) {
    int e = blockIdx.x * blockDim.x + threadIdx.x;
    if (e >= E) return;
    const double t = exp((double)out[e]);
    out[e] = (float)(t / ssum[v[e]]);
}

extern "C" void kernel_launch(void* const* d_in, const int* in_sizes, int n_in,
                              void* d_out, int out_size, void* d_ws,
                              size_t ws_size, hipStream_t stream) {
    const float* f0 = (const float*)d_in[0];
    const float* f1 = (const float*)d_in[1];
    const float* dist = (const float*)d_in[2];
    const int* u = (const int*)d_in[3];
    const int* v = (const int*)d_in[4];
    const float* wq = (const float*)d_in[5];
    const float* wj00 = (const float*)d_in[6];
    const float* wj01 = (const float*)d_in[7];
    const float* wj10 = (const float*)d_in[8];
    const float* wj11 = (const float*)d_in[9];
    const float* rW1 = (const float*)d_in[10];
    const float* rb1 = (const float*)d_in[11];
    const float* g1 = (const float*)d_in[12];
    const float* be1 = (const float*)d_in[13];
    const float* rW2 = (const float*)d_in[14];
    const float* rb2 = (const float*)d_in[15];
    const float* g2 = (const float*)d_in[16];
    const float* be2 = (const float*)d_in[17];
    const float* W3_00 = (const float*)d_in[18];
    const float* b3_00 = (const float*)d_in[19];
    const float* W3_01 = (const float*)d_in[20];
    const float* b3_01 = (const float*)d_in[21];
    const float* W3_10 = (const float*)d_in[22];
    const float* b3_10 = (const float*)d_in[23];
    const float* W3_11 = (const float*)d_in[24];
    const float* b3_11 = (const float*)d_in[25];

    const int N = in_sizes[0] / 2;  // f0 is [N,2,1]
    const int E = in_sizes[2];      // dist is [E]

    double* ssum = (double*)d_ws;
    float* out = (float*)d_out;

    hipMemsetAsync(ssum, 0, (size_t)N * sizeof(double), stream);
    const int ge = (E + EPB - 1) / EPB;
    edge_kernel<<<ge, TPB, 0, stream>>>(
        f0, f1, dist, u, v, wq, wj00, wj01, wj10, wj11, rW1, rb1, g1, be1, rW2,
        rb2, g2, be2, W3_00, b3_00, W3_01, b3_01, W3_10, b3_10, W3_11, b3_11,
        out, ssum, E);
    const int gn = (E + TPB - 1) / TPB;
    norm_kernel<<<gn, TPB, 0, stream>>>(out, v, ssum, E);
}